// Round 1
// baseline (135.297 us; speedup 1.0000x reference)
//
#include <hip/hip_runtime.h>
#include <stdint.h>

#define HIDDEN 768
#define META 25
#define EDC 300
#define BB 2
#define NMENT 2000
#define NPAIRS 40000
#define M_ROWS (BB * NMENT)       // 4000
#define M_PAD 4096                // 32 * 128
#define N_OUT 1536
#define TOTAL_PAIRS (BB * NPAIRS) // 80000
#define BK 64                     // row = 128 B = full 32-bank span (enables swizzle)

typedef __bf16 bf16x8 __attribute__((ext_vector_type(8)));
typedef float f32x4 __attribute__((ext_vector_type(4)));

static __device__ __forceinline__ float bf2f(unsigned short u) {
    union { unsigned int u; float f; } v; v.u = ((unsigned int)u) << 16; return v.f;
}
static __device__ __forceinline__ float2 bf2x(unsigned int u) {
    union { unsigned int x; float f; } lo, hi;
    lo.x = u << 16; hi.x = u & 0xffff0000u;
    float2 r; r.x = lo.f; r.y = hi.f; return r;
}
static __device__ __forceinline__ unsigned short f2bf(float f) {
    union { float f; unsigned int u; } v; v.f = f;
    unsigned int u = v.u;
    unsigned int r = (u + 0x7FFFu + ((u >> 16) & 1u)) >> 16;   // RNE
    return (unsigned short)r;
}

#define GLOAD_LDS16(g, l)                                                            \
    __builtin_amdgcn_global_load_lds((const __attribute__((address_space(1))) void*)(g), \
                                     (__attribute__((address_space(3))) void*)(l), 16, 0, 0)

// ---- fused prep: convM | convW | ed prep | W2->bf16 ----
#define NB_CONVM 3072              // (4096*768/4)/256
#define NB_CONVW 576               // 24*24
#define NB_PREP  900               // 300*768/256
#define NB_W2    3                 // 768/256

__global__ __launch_bounds__(256) void k_prep_all(
        const float* __restrict__ M, unsigned short* __restrict__ Mb,
        const float* __restrict__ W1, unsigned short* __restrict__ Wt,
        const float* __restrict__ ed_table, const float* __restrict__ b1,
        unsigned short* __restrict__ Epp,
        const float* __restrict__ W2, unsigned short* __restrict__ W2b) {
    const int blk = blockIdx.x;
    const int t = threadIdx.x;
    if (blk < NB_CONVM) {
        int idx = (blk * 256 + t) * 4;
        int row = idx / HIDDEN;
        ushort4 o;
        if (row < M_ROWS) {
            const float4 v = *(const float4*)(M + idx);
            o.x = f2bf(v.x); o.y = f2bf(v.y); o.z = f2bf(v.z); o.w = f2bf(v.w);
        } else {
            o.x = 0; o.y = 0; o.z = 0; o.w = 0;
        }
        *(ushort4*)(Mb + idx) = o;
    } else if (blk < NB_CONVM + NB_CONVW) {
        __shared__ float tile[32][68];
        int id = blk - NB_CONVM;
        int nt = id % 24, kt = id / 24;
        int n0 = nt * 64, k0 = kt * 32;
        int tk = t >> 4, tn = (t & 15) * 4;
        int srcRowOff = (n0 < HIDDEN) ? 0 : HIDDEN;
        int srcColBase = (n0 < HIDDEN) ? n0 : (n0 - HIDDEN);
        {
            const float4 v0 = *(const float4*)(W1 + (size_t)(k0 + tk + srcRowOff) * HIDDEN + srcColBase + tn);
            tile[tk][tn] = v0.x; tile[tk][tn + 1] = v0.y; tile[tk][tn + 2] = v0.z; tile[tk][tn + 3] = v0.w;
            const float4 v1 = *(const float4*)(W1 + (size_t)(k0 + tk + 16 + srcRowOff) * HIDDEN + srcColBase + tn);
            tile[tk + 16][tn] = v1.x; tile[tk + 16][tn + 1] = v1.y; tile[tk + 16][tn + 2] = v1.z; tile[tk + 16][tn + 3] = v1.w;
        }
        __syncthreads();
        int wn = t >> 2, wk = (t & 3) * 8;
        unsigned int p0 = (unsigned int)f2bf(tile[wk + 0][wn]) | ((unsigned int)f2bf(tile[wk + 1][wn]) << 16);
        unsigned int p1 = (unsigned int)f2bf(tile[wk + 2][wn]) | ((unsigned int)f2bf(tile[wk + 3][wn]) << 16);
        unsigned int p2 = (unsigned int)f2bf(tile[wk + 4][wn]) | ((unsigned int)f2bf(tile[wk + 5][wn]) << 16);
        unsigned int p3 = (unsigned int)f2bf(tile[wk + 6][wn]) | ((unsigned int)f2bf(tile[wk + 7][wn]) << 16);
        uint4 pk; pk.x = p0; pk.y = p1; pk.z = p2; pk.w = p3;
        *(uint4*)(Wt + (size_t)(n0 + wn) * HIDDEN + k0 + wk) = pk;
    } else if (blk < NB_CONVM + NB_CONVW + NB_PREP) {
        int id = (blk - NB_CONVM - NB_CONVW) * 256 + t;
        int e = id / HIDDEN, n = id - e * HIDDEN;
        float acc = b1[n];
#pragma unroll
        for (int k = 0; k < META; k++)
            acc += ed_table[e * META + k] * W1[(size_t)(2 * HIDDEN + k) * HIDDEN + n];
        Epp[id] = f2bf(acc);
    } else {
        int id = (blk - NB_CONVM - NB_CONVW - NB_PREP) * 256 + t;
        if (id < HIDDEN) W2b[id] = f2bf(W2[id]);
    }
}

// ---- AW[4096][1536] = Mb @ Wt^T ----
// 128x64 block tile, BK=64, grid 32x24 = 768 blocks = 3/CU. Swizzled LDS
// (k-line of row m rotated by (m%8)*8 shorts via global-side address) ->
// conflict-free ds_read_b128. (R7 verified: -5 us)
__global__ __launch_bounds__(256) void k_gemm(const unsigned short* __restrict__ Mb,
                                              const unsigned short* __restrict__ Wt,
                                              unsigned short* __restrict__ AW) {
    __shared__ unsigned short As[128 * BK];   // 16 KB
    __shared__ unsigned short Bs[64 * BK];    // 8 KB
    const int m0 = blockIdx.x * 128;
    const int n0 = blockIdx.y * 64;
    const int t = threadIdx.x, w = t >> 6, lane = t & 63;
    const int wm = (w & 1) * 64, wn = (w >> 1) * 32;
    const int q = lane >> 4, r = lane & 15;
    const int lrow = lane >> 3;
    const int lcol = ((((lane & 7) - lrow) & 7)) * 8;      // shorts
    const unsigned short* gA = Mb + (size_t)(m0 + w * 32 + lrow) * HIDDEN + lcol;
    const unsigned short* gB = Wt + (size_t)(n0 + w * 16 + lrow) * HIDDEN + lcol;
    unsigned short* lA = As + (w * 32) * BK;               // wave-uniform LDS base
    unsigned short* lB = Bs + (w * 16) * BK;
    f32x4 acc[4][2] = {};
    for (int k0 = 0; k0 < HIDDEN; k0 += BK) {
        GLOAD_LDS16(gA + k0, lA);
        GLOAD_LDS16(gA + k0 + 8 * HIDDEN,  lA + 8 * BK);
        GLOAD_LDS16(gA + k0 + 16 * HIDDEN, lA + 16 * BK);
        GLOAD_LDS16(gA + k0 + 24 * HIDDEN, lA + 24 * BK);
        GLOAD_LDS16(gB + k0, lB);
        GLOAD_LDS16(gB + k0 + 8 * HIDDEN,  lB + 8 * BK);
        __syncthreads();
        bf16x8 af[4][2], bfr[2][2];
        const int rs = r & 7;
#pragma unroll
        for (int i = 0; i < 4; i++)
#pragma unroll
            for (int s = 0; s < 2; s++)
                af[i][s] = *(const bf16x8*)&As[(wm + i * 16 + r) * BK + 8 * ((q + 4 * s + rs) & 7)];
#pragma unroll
        for (int j = 0; j < 2; j++)
#pragma unroll
            for (int s = 0; s < 2; s++)
                bfr[j][s] = *(const bf16x8*)&Bs[(wn + j * 16 + r) * BK + 8 * ((q + 4 * s + rs) & 7)];
#pragma unroll
        for (int i = 0; i < 4; i++)
#pragma unroll
            for (int j = 0; j < 2; j++) {
                acc[i][j] = __builtin_amdgcn_mfma_f32_16x16x32_bf16(af[i][0], bfr[j][0], acc[i][j], 0, 0, 0);
                acc[i][j] = __builtin_amdgcn_mfma_f32_16x16x32_bf16(af[i][1], bfr[j][1], acc[i][j], 0, 0, 0);
            }
        __syncthreads();
    }
    const int colb = n0 + wn + (lane & 15);
    const int rowb = m0 + wm + (lane >> 4) * 4;
#pragma unroll
    for (int i = 0; i < 4; i++)
#pragma unroll
        for (int j = 0; j < 2; j++) {
            unsigned short* dst = AW + (size_t)(rowb + i * 16) * N_OUT + colb + j * 16;
#pragma unroll
            for (int reg = 0; reg < 4; reg++)
                dst[(size_t)reg * N_OUT] = f2bf(acc[i][j][reg]);
        }
}

// ---- pair phase: 2 pairs per wave, half-wave split ----
// lanes 0-31 own pair A, lanes 32-63 own pair B. Each lane covers 24
// contiguous h-dims (3 x uint4 per stream, 48 B). Live payload = 12 uint4
// (48 VGPR) vs previous 20 (80 VGPR) -> ~6 waves/SIMD instead of ~4 for
// latency hiding on the random AW/Epp gathers. Same bytes, same coalescing
// (each load instr covers 2 rows x 512 B = identical 128B-line count).
__global__ __launch_bounds__(256, 6) void k_pair(const unsigned short* __restrict__ AW,
                                                 const unsigned short* __restrict__ Epp,
                                                 const unsigned short* __restrict__ W2b,
                                                 const float* __restrict__ b2,
                                                 const int* __restrict__ pairs,
                                                 const int* __restrict__ eds,
                                                 float* __restrict__ out) {
    const int wid = blockIdx.x * 4 + (threadIdx.x >> 6);   // 0..39999
    const int lane = threadIdx.x & 63;
    const int hl = lane & 31;
    const bool lo = lane < 32;
    const int p0 = wid * 2;                                 // even; both pairs same batch
    const size_t base = (p0 >= NPAIRS) ? (size_t)NMENT : 0;

    const int4 pr = *(const int4*)(pairs + (size_t)p0 * 2); // {m1a,m2a,m1b,m2b}
    const int2 e2 = *(const int2*)(eds + p0);
    const int m1 = lo ? pr.x : pr.z;
    const int m2 = lo ? pr.y : pr.w;
    const int ed = lo ? e2.x : e2.y;

    const int n = hl * 24;                                  // 32 lanes x 24 = 768
    const unsigned short* A1 = AW + (base + m1) * N_OUT + n;
    const unsigned short* A2 = AW + (base + m2) * N_OUT + HIDDEN + n;
    const unsigned short* EP = Epp + (size_t)ed * HIDDEN + n;
    const unsigned short* WW = W2b + n;

    // all 12 loads issued before any dependent use
    uint4 a0 = *(const uint4*)(A1);
    uint4 a1v = *(const uint4*)(A1 + 8);
    uint4 a2v = *(const uint4*)(A1 + 16);
    uint4 c0 = *(const uint4*)(A2);
    uint4 c1 = *(const uint4*)(A2 + 8);
    uint4 c2 = *(const uint4*)(A2 + 16);
    uint4 e0 = *(const uint4*)(EP);
    uint4 e1 = *(const uint4*)(EP + 8);
    uint4 e2v = *(const uint4*)(EP + 16);
    uint4 w0 = *(const uint4*)(WW);
    uint4 w1 = *(const uint4*)(WW + 8);
    uint4 w2v = *(const uint4*)(WW + 16);

    float acc = 0.f;
#define ACC2(ua, ub, ue, uw)                                                   \
    {                                                                          \
        float2 fa = bf2x(ua), fb = bf2x(ub), fe = bf2x(ue), fw = bf2x(uw);     \
        float h0 = fmaxf(fa.x + fb.x + fe.x, 0.f);                             \
        float h1 = fmaxf(fa.y + fb.y + fe.y, 0.f);                             \
        acc += h0 * fw.x + h1 * fw.y;                                          \
    }
    ACC2(a0.x, c0.x, e0.x, w0.x); ACC2(a0.y, c0.y, e0.y, w0.y);
    ACC2(a0.z, c0.z, e0.z, w0.z); ACC2(a0.w, c0.w, e0.w, w0.w);
    ACC2(a1v.x, c1.x, e1.x, w1.x); ACC2(a1v.y, c1.y, e1.y, w1.y);
    ACC2(a1v.z, c1.z, e1.z, w1.z); ACC2(a1v.w, c1.w, e1.w, w1.w);
    ACC2(a2v.x, c2.x, e2v.x, w2v.x); ACC2(a2v.y, c2.y, e2v.y, w2v.y);
    ACC2(a2v.z, c2.z, e2v.z, w2v.z); ACC2(a2v.w, c2.w, e2v.w, w2v.w);
#undef ACC2

    // half-wave butterfly (xor offsets <32 stay within each 32-lane half)
#pragma unroll
    for (int o = 16; o > 0; o >>= 1)
        acc += __shfl_xor(acc, o, 64);

    if (hl == 0)
        out[p0 + (lane >> 5)] = acc + b2[0];
}

extern "C" void kernel_launch(void* const* d_in, const int* in_sizes, int n_in,
                              void* d_out, int out_size, void* d_ws, size_t ws_size,
                              hipStream_t stream) {
    const float* mention  = (const float*)d_in[0];
    const int*   pairs    = (const int*)d_in[1];
    const int*   eds      = (const int*)d_in[2];
    const float* ed_table = (const float*)d_in[3];
    const float* W1       = (const float*)d_in[4];
    const float* b1       = (const float*)d_in[5];
    const float* W2       = (const float*)d_in[6];
    const float* b2       = (const float*)d_in[7];
    float* out = (float*)d_out;

    char* ws = (char*)d_ws;
    unsigned short* Mb  = (unsigned short*)(ws);                       // 4096*768*2  = 6,291,456
    unsigned short* Wt  = (unsigned short*)(ws + 6291456);             // 1536*768*2  = 2,359,296
    unsigned short* AW  = (unsigned short*)(ws + 8650752);             // 4096*1536*2 = 12,582,912
    unsigned short* Epp = (unsigned short*)(ws + 21233664);            // 300*768*2   = 460,800
    unsigned short* W2b = (unsigned short*)(ws + 21694464);            // 768*2

    k_prep_all<<<dim3(NB_CONVM + NB_CONVW + NB_PREP + NB_W2), dim3(256), 0, stream>>>(
        mention, Mb, W1, Wt, ed_table, b1, Epp, W2, W2b);
    k_gemm<<<dim3(M_PAD / 128, N_OUT / 64), dim3(256), 0, stream>>>(Mb, Wt, AW);
    k_pair<<<dim3(TOTAL_PAIRS / 8), dim3(256), 0, stream>>>(AW, Epp, W2b, b2, pairs, eds, out);
}

// Round 2
// 117.569 us; speedup vs baseline: 1.1508x; 1.1508x over previous
//
#include <hip/hip_runtime.h>
#include <stdint.h>

#define HIDDEN 768
#define META 25
#define EDC 300
#define BB 2
#define NMENT 2000
#define NPAIRS 40000
#define M_ROWS (BB * NMENT)       // 4000
#define M_PAD 4096                // 32 * 128
#define N_OUT 1536
#define TOTAL_PAIRS (BB * NPAIRS) // 80000
#define BK 64                     // row = 128 B = full 32-bank span (enables swizzle)

typedef __bf16 bf16x8 __attribute__((ext_vector_type(8)));
typedef float f32x4 __attribute__((ext_vector_type(4)));

static __device__ __forceinline__ float bf2f(unsigned short u) {
    union { unsigned int u; float f; } v; v.u = ((unsigned int)u) << 16; return v.f;
}
static __device__ __forceinline__ float2 bf2x(unsigned int u) {
    union { unsigned int x; float f; } lo, hi;
    lo.x = u << 16; hi.x = u & 0xffff0000u;
    float2 r; r.x = lo.f; r.y = hi.f; return r;
}
static __device__ __forceinline__ unsigned short f2bf(float f) {
    union { float f; unsigned int u; } v; v.f = f;
    unsigned int u = v.u;
    unsigned int r = (u + 0x7FFFu + ((u >> 16) & 1u)) >> 16;   // RNE
    return (unsigned short)r;
}

#define GLOAD_LDS16(g, l)                                                            \
    __builtin_amdgcn_global_load_lds((const __attribute__((address_space(1))) void*)(g), \
                                     (__attribute__((address_space(3))) void*)(l), 16, 0, 0)

// ---- fused prep: convM | convW | ed prep | W2->bf16 ----
#define NB_CONVM 3072              // (4096*768/4)/256
#define NB_CONVW 576               // 24*24
#define NB_PREP  900               // 300*768/256
#define NB_W2    3                 // 768/256

__global__ __launch_bounds__(256) void k_prep_all(
        const float* __restrict__ M, unsigned short* __restrict__ Mb,
        const float* __restrict__ W1, unsigned short* __restrict__ Wt,
        const float* __restrict__ ed_table, const float* __restrict__ b1,
        unsigned short* __restrict__ Epp,
        const float* __restrict__ W2, unsigned short* __restrict__ W2b) {
    const int blk = blockIdx.x;
    const int t = threadIdx.x;
    if (blk < NB_CONVM) {
        int idx = (blk * 256 + t) * 4;
        int row = idx / HIDDEN;
        ushort4 o;
        if (row < M_ROWS) {
            const float4 v = *(const float4*)(M + idx);
            o.x = f2bf(v.x); o.y = f2bf(v.y); o.z = f2bf(v.z); o.w = f2bf(v.w);
        } else {
            o.x = 0; o.y = 0; o.z = 0; o.w = 0;
        }
        *(ushort4*)(Mb + idx) = o;
    } else if (blk < NB_CONVM + NB_CONVW) {
        __shared__ float tile[32][68];
        int id = blk - NB_CONVM;
        int nt = id % 24, kt = id / 24;
        int n0 = nt * 64, k0 = kt * 32;
        int tk = t >> 4, tn = (t & 15) * 4;
        int srcRowOff = (n0 < HIDDEN) ? 0 : HIDDEN;
        int srcColBase = (n0 < HIDDEN) ? n0 : (n0 - HIDDEN);
        {
            const float4 v0 = *(const float4*)(W1 + (size_t)(k0 + tk + srcRowOff) * HIDDEN + srcColBase + tn);
            tile[tk][tn] = v0.x; tile[tk][tn + 1] = v0.y; tile[tk][tn + 2] = v0.z; tile[tk][tn + 3] = v0.w;
            const float4 v1 = *(const float4*)(W1 + (size_t)(k0 + tk + 16 + srcRowOff) * HIDDEN + srcColBase + tn);
            tile[tk + 16][tn] = v1.x; tile[tk + 16][tn + 1] = v1.y; tile[tk + 16][tn + 2] = v1.z; tile[tk + 16][tn + 3] = v1.w;
        }
        __syncthreads();
        int wn = t >> 2, wk = (t & 3) * 8;
        unsigned int p0 = (unsigned int)f2bf(tile[wk + 0][wn]) | ((unsigned int)f2bf(tile[wk + 1][wn]) << 16);
        unsigned int p1 = (unsigned int)f2bf(tile[wk + 2][wn]) | ((unsigned int)f2bf(tile[wk + 3][wn]) << 16);
        unsigned int p2 = (unsigned int)f2bf(tile[wk + 4][wn]) | ((unsigned int)f2bf(tile[wk + 5][wn]) << 16);
        unsigned int p3 = (unsigned int)f2bf(tile[wk + 6][wn]) | ((unsigned int)f2bf(tile[wk + 7][wn]) << 16);
        uint4 pk; pk.x = p0; pk.y = p1; pk.z = p2; pk.w = p3;
        *(uint4*)(Wt + (size_t)(n0 + wn) * HIDDEN + k0 + wk) = pk;
    } else if (blk < NB_CONVM + NB_CONVW + NB_PREP) {
        int id = (blk - NB_CONVM - NB_CONVW) * 256 + t;
        int e = id / HIDDEN, n = id - e * HIDDEN;
        float acc = b1[n];
#pragma unroll
        for (int k = 0; k < META; k++)
            acc += ed_table[e * META + k] * W1[(size_t)(2 * HIDDEN + k) * HIDDEN + n];
        Epp[id] = f2bf(acc);
    } else {
        int id = (blk - NB_CONVM - NB_CONVW - NB_PREP) * 256 + t;
        if (id < HIDDEN) W2b[id] = f2bf(W2[id]);
    }
}

// ---- AW[4096][1536] = Mb @ Wt^T ----
// 128x64 block tile, BK=64, grid 32x24 = 768 blocks = 3/CU. Swizzled LDS
// (k-line of row m rotated by (m%8)*8 shorts via global-side address) ->
// conflict-free ds_read_b128. (R7 verified: -5 us)
__global__ __launch_bounds__(256) void k_gemm(const unsigned short* __restrict__ Mb,
                                              const unsigned short* __restrict__ Wt,
                                              unsigned short* __restrict__ AW) {
    __shared__ unsigned short As[128 * BK];   // 16 KB
    __shared__ unsigned short Bs[64 * BK];    // 8 KB
    const int m0 = blockIdx.x * 128;
    const int n0 = blockIdx.y * 64;
    const int t = threadIdx.x, w = t >> 6, lane = t & 63;
    const int wm = (w & 1) * 64, wn = (w >> 1) * 32;
    const int q = lane >> 4, r = lane & 15;
    const int lrow = lane >> 3;
    const int lcol = ((((lane & 7) - lrow) & 7)) * 8;      // shorts
    const unsigned short* gA = Mb + (size_t)(m0 + w * 32 + lrow) * HIDDEN + lcol;
    const unsigned short* gB = Wt + (size_t)(n0 + w * 16 + lrow) * HIDDEN + lcol;
    unsigned short* lA = As + (w * 32) * BK;               // wave-uniform LDS base
    unsigned short* lB = Bs + (w * 16) * BK;
    f32x4 acc[4][2] = {};
    for (int k0 = 0; k0 < HIDDEN; k0 += BK) {
        GLOAD_LDS16(gA + k0, lA);
        GLOAD_LDS16(gA + k0 + 8 * HIDDEN,  lA + 8 * BK);
        GLOAD_LDS16(gA + k0 + 16 * HIDDEN, lA + 16 * BK);
        GLOAD_LDS16(gA + k0 + 24 * HIDDEN, lA + 24 * BK);
        GLOAD_LDS16(gB + k0, lB);
        GLOAD_LDS16(gB + k0 + 8 * HIDDEN,  lB + 8 * BK);
        __syncthreads();
        bf16x8 af[4][2], bfr[2][2];
        const int rs = r & 7;
#pragma unroll
        for (int i = 0; i < 4; i++)
#pragma unroll
            for (int s = 0; s < 2; s++)
                af[i][s] = *(const bf16x8*)&As[(wm + i * 16 + r) * BK + 8 * ((q + 4 * s + rs) & 7)];
#pragma unroll
        for (int j = 0; j < 2; j++)
#pragma unroll
            for (int s = 0; s < 2; s++)
                bfr[j][s] = *(const bf16x8*)&Bs[(wn + j * 16 + r) * BK + 8 * ((q + 4 * s + rs) & 7)];
#pragma unroll
        for (int i = 0; i < 4; i++)
#pragma unroll
            for (int j = 0; j < 2; j++) {
                acc[i][j] = __builtin_amdgcn_mfma_f32_16x16x32_bf16(af[i][0], bfr[j][0], acc[i][j], 0, 0, 0);
                acc[i][j] = __builtin_amdgcn_mfma_f32_16x16x32_bf16(af[i][1], bfr[j][1], acc[i][j], 0, 0, 0);
            }
        __syncthreads();
    }
    const int colb = n0 + wn + (lane & 15);
    const int rowb = m0 + wm + (lane >> 4) * 4;
#pragma unroll
    for (int i = 0; i < 4; i++)
#pragma unroll
        for (int j = 0; j < 2; j++) {
            unsigned short* dst = AW + (size_t)(rowb + i * 16) * N_OUT + colb + j * 16;
#pragma unroll
            for (int reg = 0; reg < 4; reg++)
                dst[(size_t)reg * N_OUT] = f2bf(acc[i][j][reg]);
        }
}

// ---- pair phase: 2 pairs per wave, baseline coalescing pattern ----
// chunk0 [0,512): n0 = lane*8, full wave covers one row chunk -> each uint4
// load = 64 x 16 B = 1024 B CONTIGUOUS (R1 lesson: 48B-stride lanes tripled
// L2 transactions; this keeps lanes packed at 16 B stride).
// chunk1 [512,768): lane-split — lanes 0-31 pair A's tail, 32-63 pair B's;
// 512 B contiguous per half-wave.
// Live payload: 11 uint4 (44 VGPR) vs baseline's 20 -> ~6 waves/SIMD
// (launch_bounds(256,6), cap 85 VGPR) for 2x latency hiding on the random
// AW/Epp gathers. Same bytes, same per-instruction coalescing as baseline.
__global__ __launch_bounds__(256, 6) void k_pair(const unsigned short* __restrict__ AW,
                                                 const unsigned short* __restrict__ Epp,
                                                 const unsigned short* __restrict__ W2b,
                                                 const float* __restrict__ b2,
                                                 const int* __restrict__ pairs,
                                                 const int* __restrict__ eds,
                                                 float* __restrict__ out) {
    const int wid = blockIdx.x * 4 + (threadIdx.x >> 6);   // 0..39999
    const int lane = threadIdx.x & 63;
    const int hl = lane & 31;
    const bool lo = lane < 32;
    const int p0 = wid * 2;                                 // even; both pairs same batch
    const size_t base = (p0 >= NPAIRS) ? (size_t)NMENT : 0;

    const int4 pr = *(const int4*)(pairs + (size_t)p0 * 2); // {m1a,m2a,m1b,m2b}
    const int2 e2 = *(const int2*)(eds + p0);

    const int n0 = lane * 8;              // [0,512), 16B/lane packed
    const int n1 = 512 + hl * 8;          // [512,768), 16B/lane packed per half

    const unsigned short* A1a = AW + (base + pr.x) * N_OUT;
    const unsigned short* A2a = AW + (base + pr.y) * N_OUT + HIDDEN;
    const unsigned short* EPa = Epp + (size_t)e2.x * HIDDEN;
    const unsigned short* A1b = AW + (base + pr.z) * N_OUT;
    const unsigned short* A2b = AW + (base + pr.w) * N_OUT + HIDDEN;
    const unsigned short* EPb = Epp + (size_t)e2.y * HIDDEN;

    const unsigned short* t1 = lo ? A1a : A1b;
    const unsigned short* t2 = lo ? A2a : A2b;
    const unsigned short* te = lo ? EPa : EPb;

    // all 11 loads issued before any dependent use
    uint4 w0 = *(const uint4*)(W2b + n0);
    uint4 wc = *(const uint4*)(W2b + n1);
    uint4 x1 = *(const uint4*)(A1a + n0), x2 = *(const uint4*)(A2a + n0), xe = *(const uint4*)(EPa + n0);
    uint4 y1 = *(const uint4*)(A1b + n0), y2 = *(const uint4*)(A2b + n0), ye = *(const uint4*)(EPb + n0);
    uint4 q1 = *(const uint4*)(t1 + n1),  q2 = *(const uint4*)(t2 + n1),  qe = *(const uint4*)(te + n1);

    float accA = 0.f, accB = 0.f, tacc = 0.f;
#define ACC2(acc, ua, ub, ue, uw)                                              \
    {                                                                          \
        float2 fa = bf2x(ua), fb = bf2x(ub), fe = bf2x(ue), fw = bf2x(uw);     \
        float h0 = fmaxf(fa.x + fb.x + fe.x, 0.f);                             \
        float h1 = fmaxf(fa.y + fb.y + fe.y, 0.f);                             \
        acc += h0 * fw.x + h1 * fw.y;                                          \
    }
    ACC2(accA, x1.x, x2.x, xe.x, w0.x); ACC2(accA, x1.y, x2.y, xe.y, w0.y);
    ACC2(accA, x1.z, x2.z, xe.z, w0.z); ACC2(accA, x1.w, x2.w, xe.w, w0.w);
    ACC2(accB, y1.x, y2.x, ye.x, w0.x); ACC2(accB, y1.y, y2.y, ye.y, w0.y);
    ACC2(accB, y1.z, y2.z, ye.z, w0.z); ACC2(accB, y1.w, y2.w, ye.w, w0.w);
    ACC2(tacc, q1.x, q2.x, qe.x, wc.x); ACC2(tacc, q1.y, q2.y, qe.y, wc.y);
    ACC2(tacc, q1.z, q2.z, qe.z, wc.z); ACC2(tacc, q1.w, q2.w, qe.w, wc.w);
#undef ACC2

    // full-wave reduce for chunk0 accs
#pragma unroll
    for (int o = 32; o > 0; o >>= 1) {
        accA += __shfl_xor(accA, o, 64);
        accB += __shfl_xor(accB, o, 64);
    }
    // half-wave reduce for tail acc (xor < 32 stays within each half)
#pragma unroll
    for (int o = 16; o > 0; o >>= 1)
        tacc += __shfl_xor(tacc, o, 64);
    const float tA = __shfl(tacc, 0, 64);    // pair A tail
    const float tB = __shfl(tacc, 32, 64);   // pair B tail

    if (lane == 0) {
        float bias = b2[0];
        float2 o;
        o.x = accA + tA + bias;
        o.y = accB + tB + bias;
        *(float2*)(out + p0) = o;
    }
}

extern "C" void kernel_launch(void* const* d_in, const int* in_sizes, int n_in,
                              void* d_out, int out_size, void* d_ws, size_t ws_size,
                              hipStream_t stream) {
    const float* mention  = (const float*)d_in[0];
    const int*   pairs    = (const int*)d_in[1];
    const int*   eds      = (const int*)d_in[2];
    const float* ed_table = (const float*)d_in[3];
    const float* W1       = (const float*)d_in[4];
    const float* b1       = (const float*)d_in[5];
    const float* W2       = (const float*)d_in[6];
    const float* b2       = (const float*)d_in[7];
    float* out = (float*)d_out;

    char* ws = (char*)d_ws;
    unsigned short* Mb  = (unsigned short*)(ws);                       // 4096*768*2  = 6,291,456
    unsigned short* Wt  = (unsigned short*)(ws + 6291456);             // 1536*768*2  = 2,359,296
    unsigned short* AW  = (unsigned short*)(ws + 8650752);             // 4096*1536*2 = 12,582,912
    unsigned short* Epp = (unsigned short*)(ws + 21233664);            // 300*768*2   = 460,800
    unsigned short* W2b = (unsigned short*)(ws + 21694464);            // 768*2

    k_prep_all<<<dim3(NB_CONVM + NB_CONVW + NB_PREP + NB_W2), dim3(256), 0, stream>>>(
        mention, Mb, W1, Wt, ed_table, b1, Epp, W2, W2b);
    k_gemm<<<dim3(M_PAD / 128, N_OUT / 64), dim3(256), 0, stream>>>(Mb, Wt, AW);
    k_pair<<<dim3(TOTAL_PAIRS / 8), dim3(256), 0, stream>>>(AW, Epp, W2b, b2, pairs, eds, out);
}